// Round 17
// baseline (657.385 us; speedup 1.0000x reference)
//
#include <hip/hip_runtime.h>

#define NN 100000
#define NE 600000
#define NB_SCAN 98   // 98 * 1024 = 100352 >= NN

typedef __attribute__((ext_vector_type(8))) short short8v;   // 8 bf16 (4 VGPRs)
typedef __attribute__((ext_vector_type(4))) float float4v;   // MFMA acc

// bf16 helpers (RNE; inputs are finite)
__device__ __forceinline__ unsigned short f2b(float f) {
  unsigned u = __float_as_uint(f);
  unsigned r = u + 0x7fffu + ((u >> 16) & 1u);
  return (unsigned short)(r >> 16);
}
__device__ __forceinline__ float b2f(unsigned short s) {
  return __uint_as_float((unsigned)s << 16);
}
__device__ __forceinline__ float bf_lo(unsigned p) { return __uint_as_float(p << 16); }
__device__ __forceinline__ float bf_hi(unsigned p) { return __uint_as_float(p & 0xffff0000u); }

// ---------------- degree (int atomics) ----------------
__global__ void deg_kernel(const int* __restrict__ dst, int* __restrict__ deg) {
  int i = blockIdx.x * blockDim.x + threadIdx.x;
  int n = gridDim.x * blockDim.x;
  for (; i < NE; i += n) atomicAdd(&deg[dst[i]], 1);
}

// ---------------- W -> bf16 transposed: wt[n][k] = W[k][n] ----------------
__global__ void wprep_kernel(const float* __restrict__ W1, const float* __restrict__ W2,
                             const float* __restrict__ W3, unsigned short* __restrict__ wt1,
                             unsigned short* __restrict__ wt2, unsigned short* __restrict__ wt3) {
  int t = blockIdx.x * blockDim.x + threadIdx.x;
  if (t < 16384) {
    int n = t >> 7, k = t & 127; wt1[t] = f2b(W1[k * 128 + n]);
  } else if (t < 32768) {
    int i = t - 16384; int n = i >> 7, k = i & 127; wt2[i] = f2b(W2[k * 128 + n]);
  } else if (t < 40960) {
    int i = t - 32768; int n = i >> 7, k = i & 127; wt3[i] = f2b(W3[k * 64 + n]);
  }
}

// ---------------- per-block exclusive scan: deg -> off (block-local) + dinv ----------------
__global__ __launch_bounds__(1024) void scan_blocks(const int* __restrict__ deg,
                                                    int* __restrict__ off,
                                                    int* __restrict__ bsum,
                                                    float* __restrict__ dinv) {
  __shared__ int wsum[16];
  const int t = threadIdx.x, lane = t & 63, wv = t >> 6;
  const int i = blockIdx.x * 1024 + t;
  int v = (i < NN) ? deg[i] : 0;
  if (i < NN) dinv[i] = rsqrtf((float)v + 1.0f);
  int sv = v;
  #pragma unroll
  for (int d = 1; d < 64; d <<= 1) {
    int u = __shfl_up(sv, d, 64);
    if (lane >= d) sv += u;
  }
  if (lane == 63) wsum[wv] = sv;
  __syncthreads();
  if (t < 16) {
    int w0 = wsum[t];
    #pragma unroll
    for (int d = 1; d < 16; d <<= 1) {
      int u = __shfl_up(w0, d, 64);
      if (t >= d) w0 += u;
    }
    wsum[t] = w0;
  }
  __syncthreads();
  int excl = (wv ? wsum[wv - 1] : 0) + (sv - v);
  if (i <= NN) off[i] = excl;              // block-local exclusive prefix
  if (t == 0) bsum[blockIdx.x] = wsum[15];
}

__global__ __launch_bounds__(128) void scan_bsum(int* __restrict__ bsum) {
  __shared__ int ws0;
  const int t = threadIdx.x, lane = t & 63, wv = t >> 6;
  int v = (t < NB_SCAN) ? bsum[t] : 0;
  int sv = v;
  #pragma unroll
  for (int d = 1; d < 64; d <<= 1) {
    int u = __shfl_up(sv, d, 64);
    if (lane >= d) sv += u;
  }
  if (wv == 0 && lane == 63) ws0 = sv;
  __syncthreads();
  int excl = (wv ? ws0 : 0) + (sv - v);
  if (t < NB_SCAN) bsum[t] = excl;
}

// ---------------- counting-sort fill: CSR edge list with precomputed coef ----------------
__global__ void fill_kernel(const int* __restrict__ src, const int* __restrict__ dst,
                            const float* __restrict__ dinv, const int* __restrict__ off,
                            const int* __restrict__ bsum,
                            int* __restrict__ cursor, int2* __restrict__ einfo) {
  int i = blockIdx.x * blockDim.x + threadIdx.x;
  int n = gridDim.x * blockDim.x;
  for (; i < NE; i += n) {
    int s = src[i], d = dst[i];
    int pos = off[d] + bsum[d >> 10] + atomicAdd(&cursor[d], 1);
    einfo[pos] = make_int2(s, __float_as_int(dinv[s] * dinv[d]));
  }
}

// ---------------- MFMA GEMM: 8-wave blocks share B-in-LDS; 128-row tiles ----------------
// Output h is COLUMN-SHARDED: shard s holds cols [16s,16s+16) for NOUT=128
// ([8s,8s+8) for NOUT=64), contiguous [shard][node][16] bf16 (32B rows).
template<int NOUT, bool AF32>
__global__ __launch_bounds__(512) void mfma_gemm(
    const void* __restrict__ in_, const unsigned short* __restrict__ wt,
    unsigned short* __restrict__ h, int ntiles)
{
  constexpr int NCT = NOUT / 16;
  constexpr int LDW = 136;
  __shared__ unsigned short wl[NOUT * LDW];
  __shared__ unsigned short es[8 * 16 * LDW];
  const int t = threadIdx.x;
  const int w = t >> 6, l = t & 63;
  const int r16 = l & 15, kbase = (l >> 4) * 8;

  const uint4* wt4 = (const uint4*)wt;
  #pragma unroll
  for (int i = 0; i < NOUT * 16 / 512; ++i) {
    int idx = t + i * 512;
    int n = idx >> 4, g = idx & 15;
    *(uint4*)&wl[n * LDW + g * 8] = wt4[idx];
  }
  __syncthreads();

  unsigned short* esw = &es[w * 16 * LDW];
  const float* inf = (const float*)in_;
  const unsigned short* inb = (const unsigned short*)in_;

  int tile = blockIdx.x;
  if (tile >= ntiles) return;

  float4  nf[8];
  short8v nb[4];
  {
    int grow = tile * 128 + w * 16 + r16; if (grow > NN - 1) grow = NN - 1;
    if constexpr (AF32) {
      #pragma unroll
      for (int kt = 0; kt < 4; ++kt) {
        const float* p = inf + (size_t)grow * 128 + kt * 32 + kbase;
        nf[kt * 2] = *(const float4*)p; nf[kt * 2 + 1] = *(const float4*)(p + 4);
      }
    } else {
      // input is 128-wide column-sharded: col0 = kt*32+kbase -> shard col0/16
      #pragma unroll
      for (int kt = 0; kt < 4; ++kt) {
        int col0 = kt * 32 + kbase;
        nb[kt] = *(const short8v*)(inb + (size_t)(col0 >> 4) * ((size_t)NN * 16)
                                       + (size_t)grow * 16 + (col0 & 15));
      }
    }
  }

  while (true) {
    short8v a[4];
    if constexpr (AF32) {
      #pragma unroll
      for (int kt = 0; kt < 4; ++kt) {
        float4 u0 = nf[kt * 2], u1 = nf[kt * 2 + 1];
        short8v av;
        av[0] = (short)f2b(u0.x); av[1] = (short)f2b(u0.y);
        av[2] = (short)f2b(u0.z); av[3] = (short)f2b(u0.w);
        av[4] = (short)f2b(u1.x); av[5] = (short)f2b(u1.y);
        av[6] = (short)f2b(u1.z); av[7] = (short)f2b(u1.w);
        a[kt] = av;
      }
    } else {
      #pragma unroll
      for (int kt = 0; kt < 4; ++kt) a[kt] = nb[kt];
    }

    int next = tile + gridDim.x;
    if (next < ntiles) {
      int grow = next * 128 + w * 16 + r16; if (grow > NN - 1) grow = NN - 1;
      if constexpr (AF32) {
        #pragma unroll
        for (int kt = 0; kt < 4; ++kt) {
          const float* p = inf + (size_t)grow * 128 + kt * 32 + kbase;
          nf[kt * 2] = *(const float4*)p; nf[kt * 2 + 1] = *(const float4*)(p + 4);
        }
      } else {
        #pragma unroll
        for (int kt = 0; kt < 4; ++kt) {
          int col0 = kt * 32 + kbase;
          nb[kt] = *(const short8v*)(inb + (size_t)(col0 >> 4) * ((size_t)NN * 16)
                                         + (size_t)grow * 16 + (col0 & 15));
        }
      }
    }

    float4v acc[NCT];
    #pragma unroll
    for (int c = 0; c < NCT; ++c) acc[c] = (float4v){0.f, 0.f, 0.f, 0.f};
    #pragma unroll
    for (int kt = 0; kt < 4; ++kt) {
      #pragma unroll
      for (int c = 0; c < NCT; ++c) {
        short8v b = *(const short8v*)&wl[(c * 16 + r16) * LDW + kt * 32 + kbase];
        acc[c] = __builtin_amdgcn_mfma_f32_16x16x32_bf16(a[kt], b, acc[c], 0, 0, 0);
      }
    }

    // per-wave epilogue: bf16 -> LDS -> sharded uint4 stores (rows vary fastest
    // within a 16-lane group -> 512B-contiguous runs per shard)
    const int q = l >> 4;
    #pragma unroll
    for (int c = 0; c < NCT; ++c) {
      #pragma unroll
      for (int r = 0; r < 4; ++r)
        esw[(q * 4 + r) * LDW + c * 16 + r16] = f2b(acc[c][r]);
    }
    constexpr int GPR2 = NOUT / 8;
    const int row0 = tile * 128 + w * 16;
    #pragma unroll
    for (int i = 0; i < 16 * GPR2 / 64; ++i) {
      int f = l + i * 64;
      int g = f / 16, r = f % 16;          // r fastest -> contiguous stores
      int row = row0 + r;
      if (row < NN) {
        uint4 v = *(const uint4*)&esw[r * LDW + g * 8];
        if constexpr (NOUT == 128)
          *(uint4*)(h + (size_t)(g >> 1) * ((size_t)NN * 16) + (size_t)row * 16 + (g & 1) * 8) = v;
        else
          *(uint4*)(h + (size_t)g * ((size_t)NN * 8) + (size_t)row * 8) = v;
      }
    }

    if (next >= ntiles) break;
    tile = next;
  }
}

// ---------------- aggregate, XCD-sharded: shard = blockIdx%8 -> own L2-resident slice ----
// wave per (node, shard); 8(16) edge-slots x 8(4) lanes; 2-deep ILP; shfl reduce.
template<int NOUT, bool BF16RELU>
__global__ __launch_bounds__(256) void agg_kernel(
    const unsigned short* __restrict__ h, const int* __restrict__ off,
    const int* __restrict__ bsum, const int2* __restrict__ einfo,
    const float* __restrict__ dinv, const float* __restrict__ bias,
    void* __restrict__ out_)
{
  constexpr int CPL = NOUT / 16;        // uints per shard row: 8 (128) or 4 (64)
  constexpr int GS  = 64 / CPL;         // edge slots: 8 or 16
  const int shard = blockIdx.x & 7;
  const int w = (blockIdx.x >> 3) * 4 + (int)(threadIdx.x >> 6);
  if (w >= NN) return;
  const int lane = threadIdx.x & 63;
  const int slot = lane / CPL;
  const int c = lane % CPL;
  const int n0 = off[w] + bsum[w >> 10];
  const int n1 = off[w + 1] + bsum[(w + 1) >> 10];
  const unsigned* hs = (const unsigned*)h + (size_t)shard * NN * CPL;

  float a0 = 0.f, a1 = 0.f;
  for (int e = n0; e < n1; e += 2 * GS) {
    int e0 = e + slot, e1 = e + GS + slot;
    bool ok0 = e0 < n1, ok1 = e1 < n1;
    int2 s0 = einfo[ok0 ? e0 : n0];
    int2 s1 = einfo[ok1 ? e1 : n0];
    float c0 = ok0 ? __int_as_float(s0.y) : 0.f;
    float c1 = ok1 ? __int_as_float(s1.y) : 0.f;
    unsigned v0 = hs[(size_t)s0.x * CPL + c];
    unsigned v1 = hs[(size_t)s1.x * CPL + c];
    a0 = fmaf(bf_lo(v0), c0, a0);
    a1 = fmaf(bf_hi(v0), c0, a1);
    a0 = fmaf(bf_lo(v1), c1, a0);
    a1 = fmaf(bf_hi(v1), c1, a1);
  }
  #pragma unroll
  for (int m = CPL; m < 64; m <<= 1) {
    a0 += __shfl_xor(a0, m, 64);
    a1 += __shfl_xor(a1, m, 64);
  }
  if (slot == 0) {
    const float di = dinv[w];
    const float di2 = di * di;
    unsigned sv = hs[(size_t)w * CPL + c];
    float2 bv = ((const float2*)bias)[shard * CPL + c];
    float o0 = fmaf(bf_lo(sv), di2, bv.x) + a0;
    float o1 = fmaf(bf_hi(sv), di2, bv.y) + a1;
    if constexpr (BF16RELU) {
      unsigned o = (unsigned)f2b(fmaxf(o0, 0.f)) | ((unsigned)f2b(fmaxf(o1, 0.f)) << 16);
      ((unsigned*)out_)[(size_t)shard * NN * CPL + (size_t)w * CPL + c] = o;
    } else {
      float2 o; o.x = o0; o.y = o1;
      ((float2*)out_)[(size_t)w * (NOUT / 2) + shard * CPL + c] = o;   // row-major f32
    }
  }
}

extern "C" void kernel_launch(void* const* d_in, const int* in_sizes, int n_in,
                              void* d_out, int out_size, void* d_ws, size_t ws_size,
                              hipStream_t stream) {
  const float* x  = (const float*)d_in[0];
  const int*   ei = (const int*)d_in[1];
  const float* W1 = (const float*)d_in[2];
  const float* b1 = (const float*)d_in[3];
  const float* W2 = (const float*)d_in[4];
  const float* b2 = (const float*)d_in[5];
  const float* W3 = (const float*)d_in[6];
  const float* b3 = (const float*)d_in[7];
  float* out = (float*)d_out;

  const int* src = ei;
  const int* dst = ei + NE;

  // workspace layout (float elements)
  float* ws = (float*)d_ws;
  int*   deg    = (int*)ws;                         // NN
  float* dinv   = ws + NN;                          // NN
  int*   off    = (int*)(ws + 2 * NN);              // NN+4
  int*   cursor = (int*)(ws + 3 * NN + 4);          // NN
  int*   bsum   = (int*)(ws + 4 * NN + 4);          // 128
  int2*  einfo  = (int2*)(ws + 4 * NN + 132);       // NE int2
  unsigned short* wt1 = (unsigned short*)(ws + 4 * NN + 132 + 2 * NE);  // 16384 bf16
  unsigned short* wt2 = wt1 + 16384;
  unsigned short* wt3 = wt2 + 16384;
  unsigned short* hA  = (unsigned short*)(ws + 4 * NN + 132 + 2 * NE + 20480); // NN*128 bf16
  unsigned short* hB  = hA + (size_t)NN * 128;                                 // NN*128 bf16

  hipMemsetAsync(deg, 0, NN * sizeof(int), stream);
  hipMemsetAsync(cursor, 0, NN * sizeof(int), stream);
  wprep_kernel<<<160, 256, 0, stream>>>(W1, W2, W3, wt1, wt2, wt3);
  deg_kernel<<<1024, 256, 0, stream>>>(dst, deg);
  scan_blocks<<<NB_SCAN, 1024, 0, stream>>>(deg, off, bsum, dinv);
  scan_bsum<<<1, 128, 0, stream>>>(bsum);
  fill_kernel<<<1024, 256, 0, stream>>>(src, dst, dinv, off, bsum, cursor, einfo);

  const int AGG_GRID = 8 * ((NN + 3) / 4);        // (node-quad, shard) blocks
  const int NT = (NN + 127) / 128;                // 782 row tiles (128 rows)
  const int GEMM_GRID = 391;                      // exactly 2 tiles per block

  // layer 1
  mfma_gemm<128, true><<<GEMM_GRID, 512, 0, stream>>>(x, wt1, hA, NT);
  agg_kernel<128, true><<<AGG_GRID, 256, 0, stream>>>(hA, off, bsum, einfo, dinv, b1, hB);
  // layer 2
  mfma_gemm<128, false><<<GEMM_GRID, 512, 0, stream>>>(hB, wt2, hA, NT);
  agg_kernel<128, true><<<AGG_GRID, 256, 0, stream>>>(hA, off, bsum, einfo, dinv, b2, hB);
  // layer 3 (64-wide, f32 final out)
  mfma_gemm<64, false><<<GEMM_GRID, 512, 0, stream>>>(hB, wt3, hA, NT);
  agg_kernel<64, false><<<AGG_GRID, 256, 0, stream>>>(hA, off, bsum, einfo, dinv, b3, out);
}

// Round 20
// 233.661 us; speedup vs baseline: 2.8134x; 2.8134x over previous
//
#include <hip/hip_runtime.h>

#define NN 100000
#define NE 600000
#define NB_SCAN 98   // 98 * 1024 = 100352 >= NN

typedef __attribute__((ext_vector_type(8))) short short8v;   // 8 bf16 (4 VGPRs)
typedef __attribute__((ext_vector_type(4))) float float4v;   // MFMA acc

// bf16 helpers (RNE; inputs are finite)
__device__ __forceinline__ unsigned short f2b(float f) {
  unsigned u = __float_as_uint(f);
  unsigned r = u + 0x7fffu + ((u >> 16) & 1u);
  return (unsigned short)(r >> 16);
}
__device__ __forceinline__ float bf_lo(unsigned p) { return __uint_as_float(p << 16); }
__device__ __forceinline__ float bf_hi(unsigned p) { return __uint_as_float(p & 0xffff0000u); }

// ---------------- degree (int atomics) ----------------
__global__ void deg_kernel(const int* __restrict__ dst, int* __restrict__ deg) {
  int i = blockIdx.x * blockDim.x + threadIdx.x;
  int n = gridDim.x * blockDim.x;
  for (; i < NE; i += n) atomicAdd(&deg[dst[i]], 1);
}

// ---------------- W -> bf16 transposed: wt[n][k] = W[k][n] ----------------
__global__ void wprep_kernel(const float* __restrict__ W1, const float* __restrict__ W2,
                             const float* __restrict__ W3, unsigned short* __restrict__ wt1,
                             unsigned short* __restrict__ wt2, unsigned short* __restrict__ wt3) {
  int t = blockIdx.x * blockDim.x + threadIdx.x;
  if (t < 16384) {
    int n = t >> 7, k = t & 127; wt1[t] = f2b(W1[k * 128 + n]);
  } else if (t < 32768) {
    int i = t - 16384; int n = i >> 7, k = i & 127; wt2[i] = f2b(W2[k * 128 + n]);
  } else if (t < 40960) {
    int i = t - 32768; int n = i >> 7, k = i & 127; wt3[i] = f2b(W3[k * 64 + n]);
  }
}

// ---------------- per-block exclusive scan: deg -> off (block-local) + dinv ----------------
__global__ __launch_bounds__(1024) void scan_blocks(const int* __restrict__ deg,
                                                    int* __restrict__ off,
                                                    int* __restrict__ bsum,
                                                    float* __restrict__ dinv) {
  __shared__ int wsum[16];
  const int t = threadIdx.x, lane = t & 63, wv = t >> 6;
  const int i = blockIdx.x * 1024 + t;
  int v = (i < NN) ? deg[i] : 0;
  if (i < NN) dinv[i] = rsqrtf((float)v + 1.0f);
  int sv = v;
  #pragma unroll
  for (int d = 1; d < 64; d <<= 1) {
    int u = __shfl_up(sv, d, 64);
    if (lane >= d) sv += u;
  }
  if (lane == 63) wsum[wv] = sv;
  __syncthreads();
  if (t < 16) {
    int w0 = wsum[t];
    #pragma unroll
    for (int d = 1; d < 16; d <<= 1) {
      int u = __shfl_up(w0, d, 64);
      if (t >= d) w0 += u;
    }
    wsum[t] = w0;
  }
  __syncthreads();
  int excl = (wv ? wsum[wv - 1] : 0) + (sv - v);
  if (i <= NN) off[i] = excl;              // block-local exclusive prefix
  if (t == 0) bsum[blockIdx.x] = wsum[15];
}

__global__ __launch_bounds__(128) void scan_bsum(int* __restrict__ bsum) {
  __shared__ int ws0;
  const int t = threadIdx.x, lane = t & 63, wv = t >> 6;
  int v = (t < NB_SCAN) ? bsum[t] : 0;
  int sv = v;
  #pragma unroll
  for (int d = 1; d < 64; d <<= 1) {
    int u = __shfl_up(sv, d, 64);
    if (lane >= d) sv += u;
  }
  if (wv == 0 && lane == 63) ws0 = sv;
  __syncthreads();
  int excl = (wv ? ws0 : 0) + (sv - v);
  if (t < NB_SCAN) bsum[t] = excl;
}

// ---------------- counting-sort fill: CSR edge list with precomputed coef ----------------
__global__ void fill_kernel(const int* __restrict__ src, const int* __restrict__ dst,
                            const float* __restrict__ dinv, const int* __restrict__ off,
                            const int* __restrict__ bsum,
                            int* __restrict__ cursor, int2* __restrict__ einfo) {
  int i = blockIdx.x * blockDim.x + threadIdx.x;
  int n = gridDim.x * blockDim.x;
  for (; i < NE; i += n) {
    int s = src[i], d = dst[i];
    int pos = off[d] + bsum[d >> 10] + atomicAdd(&cursor[d], 1);
    einfo[pos] = make_int2(s, __float_as_int(dinv[s] * dinv[d]));
  }
}

// ---------------- layer-1 MFMA GEMM: 8-wave blocks, B in LDS, row-major bf16 out ----------------
__global__ __launch_bounds__(512) void mfma_gemm1(
    const float* __restrict__ inf, const unsigned short* __restrict__ wt,
    unsigned short* __restrict__ h, int ntiles)
{
  constexpr int NCT = 8;
  constexpr int LDW = 136;
  __shared__ unsigned short wl[128 * LDW];
  __shared__ unsigned short es[8 * 16 * LDW];
  const int t = threadIdx.x;
  const int w = t >> 6, l = t & 63;
  const int r16 = l & 15, kbase = (l >> 4) * 8;

  const uint4* wt4 = (const uint4*)wt;
  #pragma unroll
  for (int i = 0; i < 4; ++i) {
    int idx = t + i * 512;
    int n = idx >> 4, g = idx & 15;
    *(uint4*)&wl[n * LDW + g * 8] = wt4[idx];
  }
  __syncthreads();

  unsigned short* esw = &es[w * 16 * LDW];
  int tile = blockIdx.x;
  if (tile >= ntiles) return;

  float4 nf[8];
  {
    int grow = tile * 128 + w * 16 + r16; if (grow > NN - 1) grow = NN - 1;
    #pragma unroll
    for (int kt = 0; kt < 4; ++kt) {
      const float* p = inf + (size_t)grow * 128 + kt * 32 + kbase;
      nf[kt * 2] = *(const float4*)p; nf[kt * 2 + 1] = *(const float4*)(p + 4);
    }
  }

  while (true) {
    short8v a[4];
    #pragma unroll
    for (int kt = 0; kt < 4; ++kt) {
      float4 u0 = nf[kt * 2], u1 = nf[kt * 2 + 1];
      short8v av;
      av[0] = (short)f2b(u0.x); av[1] = (short)f2b(u0.y);
      av[2] = (short)f2b(u0.z); av[3] = (short)f2b(u0.w);
      av[4] = (short)f2b(u1.x); av[5] = (short)f2b(u1.y);
      av[6] = (short)f2b(u1.z); av[7] = (short)f2b(u1.w);
      a[kt] = av;
    }

    int next = tile + gridDim.x;
    if (next < ntiles) {
      int grow = next * 128 + w * 16 + r16; if (grow > NN - 1) grow = NN - 1;
      #pragma unroll
      for (int kt = 0; kt < 4; ++kt) {
        const float* p = inf + (size_t)grow * 128 + kt * 32 + kbase;
        nf[kt * 2] = *(const float4*)p; nf[kt * 2 + 1] = *(const float4*)(p + 4);
      }
    }

    float4v acc[NCT];
    #pragma unroll
    for (int c = 0; c < NCT; ++c) acc[c] = (float4v){0.f, 0.f, 0.f, 0.f};
    #pragma unroll
    for (int kt = 0; kt < 4; ++kt) {
      #pragma unroll
      for (int c = 0; c < NCT; ++c) {
        short8v b = *(const short8v*)&wl[(c * 16 + r16) * LDW + kt * 32 + kbase];
        acc[c] = __builtin_amdgcn_mfma_f32_16x16x32_bf16(a[kt], b, acc[c], 0, 0, 0);
      }
    }

    const int q = l >> 4;
    #pragma unroll
    for (int c = 0; c < NCT; ++c) {
      #pragma unroll
      for (int r = 0; r < 4; ++r)
        esw[(q * 4 + r) * LDW + c * 16 + r16] = f2b(acc[c][r]);
    }
    const int row0 = tile * 128 + w * 16;
    #pragma unroll
    for (int i = 0; i < 4; ++i) {
      int f = l + i * 64;
      int r = f >> 4, g = f & 15;
      int row = row0 + r;
      if (row < NN)
        *(uint4*)(h + (size_t)row * 128 + g * 8) = *(const uint4*)&esw[r * LDW + g * 8];
    }

    if (next >= ntiles) break;
    tile = next;
  }
}

// ---------------- fused agg + next-layer GEMM ----------------
// Block = 256 thr / 4 waves / 16 nodes. Each wave aggregates 4 nodes
// (quad-edge, 2-deep ILP), writes relu(b + dinv^2 h + sum coef h) rows as
// bf16 to LDS; barrier; 16-row x NOUTG MFMA with W held in registers.
template<int NOUTG>
__global__ __launch_bounds__(256) void fused_agg_gemm(
    const unsigned short* __restrict__ h, const int* __restrict__ off,
    const int* __restrict__ bsum, const int2* __restrict__ einfo,
    const float* __restrict__ dinv, const float* __restrict__ bias,
    const unsigned short* __restrict__ wt, unsigned short* __restrict__ hout)
{
  constexpr int CPW = NOUTG / 64;          // col-frags per wave: 2 or 1
  __shared__ unsigned short xs[16 * 136];  // aggregated rows (bf16)
  __shared__ unsigned short es[16 * 136];  // epilogue transpose
  const int t = threadIdx.x;
  const int wv = t >> 6, l = t & 63;
  const int node0 = blockIdx.x * 16;

  // B fragments in registers (global, L2-hot): wave wv covers cols [wv*CPW*16 ..)
  short8v bfrag[CPW][4];
  {
    const int col = l & 15, kb = (l >> 4) * 8;
    #pragma unroll
    for (int cc = 0; cc < CPW; ++cc)
      #pragma unroll
      for (int kt = 0; kt < 4; ++kt)
        bfrag[cc][kt] = *(const short8v*)(wt +
            ((size_t)(wv * CPW + cc) * 16 + col) * 128 + kt * 32 + kb);
  }

  const int g = l >> 4;       // edge slot 0..3
  const int c = l & 15;       // uint4 col id (cols [8c,8c+8))
  const uint4* hu4 = (const uint4*)h;

  #pragma unroll 1
  for (int q = 0; q < 4; ++q) {
    const int w = node0 + wv * 4 + q;
    const int n0 = off[w] + bsum[w >> 10];
    const int n1 = off[w + 1] + bsum[(w + 1) >> 10];
    float acc[8];
    if (g == 0) {
      const float di = dinv[w];
      const float di2 = di * di;
      uint4 sv = hu4[(size_t)w * 16 + c];
      const float4* b4 = (const float4*)bias;
      float4 bl = b4[c * 2], bh = b4[c * 2 + 1];
      acc[0] = fmaf(bf_lo(sv.x), di2, bl.x);
      acc[1] = fmaf(bf_hi(sv.x), di2, bl.y);
      acc[2] = fmaf(bf_lo(sv.y), di2, bl.z);
      acc[3] = fmaf(bf_hi(sv.y), di2, bl.w);
      acc[4] = fmaf(bf_lo(sv.z), di2, bh.x);
      acc[5] = fmaf(bf_hi(sv.z), di2, bh.y);
      acc[6] = fmaf(bf_lo(sv.w), di2, bh.z);
      acc[7] = fmaf(bf_hi(sv.w), di2, bh.w);
    } else {
      #pragma unroll
      for (int j = 0; j < 8; ++j) acc[j] = 0.f;
    }

    for (int e = n0; e < n1; e += 8) {
      int e0 = e + g, e1 = e + 4 + g;
      bool ok0 = e0 < n1, ok1 = e1 < n1;
      int2 s0 = einfo[ok0 ? e0 : n0];
      int2 s1 = einfo[ok1 ? e1 : n0];
      float c0 = ok0 ? __int_as_float(s0.y) : 0.f;
      float c1 = ok1 ? __int_as_float(s1.y) : 0.f;
      uint4 v0 = hu4[(size_t)s0.x * 16 + c];
      uint4 v1 = hu4[(size_t)s1.x * 16 + c];
      acc[0] = fmaf(bf_lo(v0.x), c0, acc[0]);
      acc[1] = fmaf(bf_hi(v0.x), c0, acc[1]);
      acc[2] = fmaf(bf_lo(v0.y), c0, acc[2]);
      acc[3] = fmaf(bf_hi(v0.y), c0, acc[3]);
      acc[4] = fmaf(bf_lo(v0.z), c0, acc[4]);
      acc[5] = fmaf(bf_hi(v0.z), c0, acc[5]);
      acc[6] = fmaf(bf_lo(v0.w), c0, acc[6]);
      acc[7] = fmaf(bf_hi(v0.w), c0, acc[7]);
      acc[0] = fmaf(bf_lo(v1.x), c1, acc[0]);
      acc[1] = fmaf(bf_hi(v1.x), c1, acc[1]);
      acc[2] = fmaf(bf_lo(v1.y), c1, acc[2]);
      acc[3] = fmaf(bf_hi(v1.y), c1, acc[3]);
      acc[4] = fmaf(bf_lo(v1.z), c1, acc[4]);
      acc[5] = fmaf(bf_hi(v1.z), c1, acc[5]);
      acc[6] = fmaf(bf_lo(v1.w), c1, acc[6]);
      acc[7] = fmaf(bf_hi(v1.w), c1, acc[7]);
    }

    #pragma unroll
    for (int j = 0; j < 8; ++j) {
      acc[j] += __shfl_xor(acc[j], 16, 64);
      acc[j] += __shfl_xor(acc[j], 32, 64);
    }

    if (g == 0) {
      uint4 o;
      o.x = (unsigned)f2b(fmaxf(acc[0], 0.f)) | ((unsigned)f2b(fmaxf(acc[1], 0.f)) << 16);
      o.y = (unsigned)f2b(fmaxf(acc[2], 0.f)) | ((unsigned)f2b(fmaxf(acc[3], 0.f)) << 16);
      o.z = (unsigned)f2b(fmaxf(acc[4], 0.f)) | ((unsigned)f2b(fmaxf(acc[5], 0.f)) << 16);
      o.w = (unsigned)f2b(fmaxf(acc[6], 0.f)) | ((unsigned)f2b(fmaxf(acc[7], 0.f)) << 16);
      *(uint4*)&xs[(wv * 4 + q) * 136 + c * 8] = o;
    }
  }
  __syncthreads();

  // MFMA: 16 rows (xs) x NOUTG cols (bfrag)
  short8v a[4];
  {
    const int kb = (l >> 4) * 8;
    #pragma unroll
    for (int kt = 0; kt < 4; ++kt)
      a[kt] = *(const short8v*)&xs[(l & 15) * 136 + kt * 32 + kb];
  }
  float4v acg[CPW];
  #pragma unroll
  for (int cc = 0; cc < CPW; ++cc) acg[cc] = (float4v){0.f, 0.f, 0.f, 0.f};
  #pragma unroll
  for (int kt = 0; kt < 4; ++kt)
    #pragma unroll
    for (int cc = 0; cc < CPW; ++cc)
      acg[cc] = __builtin_amdgcn_mfma_f32_16x16x32_bf16(a[kt], bfrag[cc][kt], acg[cc], 0, 0, 0);

  const int qq = l >> 4, c16 = l & 15;
  #pragma unroll
  for (int cc = 0; cc < CPW; ++cc)
    #pragma unroll
    for (int r = 0; r < 4; ++r)
      es[(qq * 4 + r) * 136 + (wv * CPW + cc) * 16 + c16] = f2b(acg[cc][r]);
  __syncthreads();

  constexpr int GPR = NOUTG / 8;   // uint4 groups per row
  if (t < 16 * GPR) {
    int row = t / GPR, gg = t % GPR;
    *(uint4*)(hout + (size_t)(node0 + row) * NOUTG + gg * 8) =
        *(const uint4*)&es[row * 136 + gg * 8];
  }
}

// ---------------- final aggregate (64-wide, f32 out, no relu) ----------------
__global__ __launch_bounds__(256) void agg_final(
    const unsigned short* __restrict__ h, const int* __restrict__ off,
    const int* __restrict__ bsum, const int2* __restrict__ einfo,
    const float* __restrict__ dinv, const float* __restrict__ bias,
    float* __restrict__ out)
{
  const int w = (int)((blockIdx.x * 256 + threadIdx.x) >> 6);
  if (w >= NN) return;
  const int lane = threadIdx.x & 63;
  const int g = lane >> 3;            // edge slot 0..7
  const int c = lane & 7;             // uint4 col id (cols [8c,8c+8))
  const int n0 = off[w] + bsum[w >> 10];
  const int n1 = off[w + 1] + bsum[(w + 1) >> 10];
  const uint4* hu4 = (const uint4*)h;

  float acc[8];
  if (g == 0) {
    const float di = dinv[w];
    const float di2 = di * di;
    uint4 sv = hu4[(size_t)w * 8 + c];
    const float4* b4 = (const float4*)bias;
    float4 bl = b4[c * 2], bh = b4[c * 2 + 1];
    acc[0] = fmaf(bf_lo(sv.x), di2, bl.x);
    acc[1] = fmaf(bf_hi(sv.x), di2, bl.y);
    acc[2] = fmaf(bf_lo(sv.y), di2, bl.z);
    acc[3] = fmaf(bf_hi(sv.y), di2, bl.w);
    acc[4] = fmaf(bf_lo(sv.z), di2, bh.x);
    acc[5] = fmaf(bf_hi(sv.z), di2, bh.y);
    acc[6] = fmaf(bf_lo(sv.w), di2, bh.z);
    acc[7] = fmaf(bf_hi(sv.w), di2, bh.w);
  } else {
    #pragma unroll
    for (int j = 0; j < 8; ++j) acc[j] = 0.f;
  }

  for (int e = n0; e < n1; e += 16) {
    int e0 = e + g, e1 = e + 8 + g;
    bool ok0 = e0 < n1, ok1 = e1 < n1;
    int2 s0 = einfo[ok0 ? e0 : n0];
    int2 s1 = einfo[ok1 ? e1 : n0];
    float c0 = ok0 ? __int_as_float(s0.y) : 0.f;
    float c1 = ok1 ? __int_as_float(s1.y) : 0.f;
    uint4 v0 = hu4[(size_t)s0.x * 8 + c];
    uint4 v1 = hu4[(size_t)s1.x * 8 + c];
    acc[0] = fmaf(bf_lo(v0.x), c0, acc[0]);
    acc[1] = fmaf(bf_hi(v0.x), c0, acc[1]);
    acc[2] = fmaf(bf_lo(v0.y), c0, acc[2]);
    acc[3] = fmaf(bf_hi(v0.y), c0, acc[3]);
    acc[4] = fmaf(bf_lo(v0.z), c0, acc[4]);
    acc[5] = fmaf(bf_hi(v0.z), c0, acc[5]);
    acc[6] = fmaf(bf_lo(v0.w), c0, acc[6]);
    acc[7] = fmaf(bf_hi(v0.w), c0, acc[7]);
    acc[0] = fmaf(bf_lo(v1.x), c1, acc[0]);
    acc[1] = fmaf(bf_hi(v1.x), c1, acc[1]);
    acc[2] = fmaf(bf_lo(v1.y), c1, acc[2]);
    acc[3] = fmaf(bf_hi(v1.y), c1, acc[3]);
    acc[4] = fmaf(bf_lo(v1.z), c1, acc[4]);
    acc[5] = fmaf(bf_hi(v1.z), c1, acc[5]);
    acc[6] = fmaf(bf_lo(v1.w), c1, acc[6]);
    acc[7] = fmaf(bf_hi(v1.w), c1, acc[7]);
  }

  #pragma unroll
  for (int j = 0; j < 8; ++j) {
    acc[j] += __shfl_xor(acc[j], 8, 64);
    acc[j] += __shfl_xor(acc[j], 16, 64);
    acc[j] += __shfl_xor(acc[j], 32, 64);
  }

  if (g == 0) {
    float4 o0, o1;
    o0.x = acc[0]; o0.y = acc[1]; o0.z = acc[2]; o0.w = acc[3];
    o1.x = acc[4]; o1.y = acc[5]; o1.z = acc[6]; o1.w = acc[7];
    ((float4*)out)[(size_t)w * 16 + c * 2]     = o0;
    ((float4*)out)[(size_t)w * 16 + c * 2 + 1] = o1;
  }
}

extern "C" void kernel_launch(void* const* d_in, const int* in_sizes, int n_in,
                              void* d_out, int out_size, void* d_ws, size_t ws_size,
                              hipStream_t stream) {
  const float* x  = (const float*)d_in[0];
  const int*   ei = (const int*)d_in[1];
  const float* W1 = (const float*)d_in[2];
  const float* b1 = (const float*)d_in[3];
  const float* W2 = (const float*)d_in[4];
  const float* b2 = (const float*)d_in[5];
  const float* W3 = (const float*)d_in[6];
  const float* b3 = (const float*)d_in[7];
  float* out = (float*)d_out;

  const int* src = ei;
  const int* dst = ei + NE;

  // workspace layout (float elements)
  float* ws = (float*)d_ws;
  int*   deg    = (int*)ws;                         // NN
  float* dinv   = ws + NN;                          // NN
  int*   off    = (int*)(ws + 2 * NN);              // NN+4
  int*   cursor = (int*)(ws + 3 * NN + 4);          // NN
  int*   bsum   = (int*)(ws + 4 * NN + 4);          // 128
  int2*  einfo  = (int2*)(ws + 4 * NN + 132);       // NE int2
  unsigned short* wt1 = (unsigned short*)(ws + 4 * NN + 132 + 2 * NE);  // 16384 bf16
  unsigned short* wt2 = wt1 + 16384;
  unsigned short* wt3 = wt2 + 16384;
  unsigned short* hA  = (unsigned short*)(ws + 4 * NN + 132 + 2 * NE + 20480); // NN*128 bf16
  unsigned short* hB  = hA + (size_t)NN * 128;                                 // NN*128 bf16

  hipMemsetAsync(deg, 0, NN * sizeof(int), stream);
  hipMemsetAsync(cursor, 0, NN * sizeof(int), stream);
  wprep_kernel<<<160, 256, 0, stream>>>(W1, W2, W3, wt1, wt2, wt3);
  deg_kernel<<<1024, 256, 0, stream>>>(dst, deg);
  scan_blocks<<<NB_SCAN, 1024, 0, stream>>>(deg, off, bsum, dinv);
  scan_bsum<<<1, 128, 0, stream>>>(bsum);
  fill_kernel<<<1024, 256, 0, stream>>>(src, dst, dinv, off, bsum, cursor, einfo);

  const int NT = (NN + 127) / 128;                // 782 row tiles (128 rows)
  const int GEMM_GRID = 391;                      // 2 tiles per block
  const int FUSE_GRID = NN / 16;                  // 6250 blocks (16 nodes each)
  const int AGG_GRID = (NN * 64 + 255) / 256;     // one wave per node

  // layer 1 GEMM: hA = x @ W1 (bf16 row-major)
  mfma_gemm1<<<GEMM_GRID, 512, 0, stream>>>(x, wt1, hA, NT);
  // fused: hB = relu(agg(hA) + b1) @ W2
  fused_agg_gemm<128><<<FUSE_GRID, 256, 0, stream>>>(hA, off, bsum, einfo, dinv, b1, wt2, hB);
  // fused: hA = relu(agg(hB) + b2) @ W3   (64-wide)
  fused_agg_gemm<64><<<FUSE_GRID, 256, 0, stream>>>(hB, off, bsum, einfo, dinv, b2, wt3, hA);
  // final aggregate: out = agg(hA) + b3 (f32)
  agg_final<<<AGG_GRID, 256, 0, stream>>>(hA, off, bsum, einfo, dinv, b3, out);
}

// Round 21
// 220.269 us; speedup vs baseline: 2.9845x; 1.0608x over previous
//
#include <hip/hip_runtime.h>

#define NN 100000
#define NE 600000
#define NB_SCAN 98   // 98 * 1024 = 100352 >= NN

typedef __attribute__((ext_vector_type(8))) short short8v;   // 8 bf16 (4 VGPRs)
typedef __attribute__((ext_vector_type(4))) float float4v;   // MFMA acc

// bf16 helpers (RNE; inputs are finite)
__device__ __forceinline__ unsigned short f2b(float f) {
  unsigned u = __float_as_uint(f);
  unsigned r = u + 0x7fffu + ((u >> 16) & 1u);
  return (unsigned short)(r >> 16);
}
__device__ __forceinline__ float b2f(unsigned short s) {
  return __uint_as_float((unsigned)s << 16);
}
__device__ __forceinline__ float bf_lo(unsigned p) { return __uint_as_float(p << 16); }
__device__ __forceinline__ float bf_hi(unsigned p) { return __uint_as_float(p & 0xffff0000u); }

// ---------------- degree (int atomics) ----------------
__global__ void deg_kernel(const int* __restrict__ dst, int* __restrict__ deg) {
  int i = blockIdx.x * blockDim.x + threadIdx.x;
  int n = gridDim.x * blockDim.x;
  for (; i < NE; i += n) atomicAdd(&deg[dst[i]], 1);
}

// ---------------- W -> bf16 transposed: wt[n][k] = W[k][n] ----------------
__global__ void wprep_kernel(const float* __restrict__ W1, const float* __restrict__ W2,
                             const float* __restrict__ W3, unsigned short* __restrict__ wt1,
                             unsigned short* __restrict__ wt2, unsigned short* __restrict__ wt3) {
  int t = blockIdx.x * blockDim.x + threadIdx.x;
  if (t < 16384) {
    int n = t >> 7, k = t & 127; wt1[t] = f2b(W1[k * 128 + n]);
  } else if (t < 32768) {
    int i = t - 16384; int n = i >> 7, k = i & 127; wt2[i] = f2b(W2[k * 128 + n]);
  } else if (t < 40960) {
    int i = t - 32768; int n = i >> 7, k = i & 127; wt3[i] = f2b(W3[k * 64 + n]);
  }
}

// ---------------- hierarchical exclusive scan: deg -> off (+ fused dinv) ----------------
__global__ __launch_bounds__(1024) void scan_blocks(const int* __restrict__ deg,
                                                    int* __restrict__ off,
                                                    int* __restrict__ bsum,
                                                    float* __restrict__ dinv) {
  __shared__ int wsum[16];
  const int t = threadIdx.x, lane = t & 63, wv = t >> 6;
  const int i = blockIdx.x * 1024 + t;
  int v = (i < NN) ? deg[i] : 0;
  if (i < NN) dinv[i] = rsqrtf((float)v + 1.0f);
  int sv = v;
  #pragma unroll
  for (int d = 1; d < 64; d <<= 1) {
    int u = __shfl_up(sv, d, 64);
    if (lane >= d) sv += u;
  }
  if (lane == 63) wsum[wv] = sv;
  __syncthreads();
  if (t < 16) {
    int w0 = wsum[t];
    #pragma unroll
    for (int d = 1; d < 16; d <<= 1) {
      int u = __shfl_up(w0, d, 64);
      if (t >= d) w0 += u;
    }
    wsum[t] = w0;
  }
  __syncthreads();
  int excl = (wv ? wsum[wv - 1] : 0) + (sv - v);
  if (i < NN) off[i] = excl;
  if (t == 0) bsum[blockIdx.x] = wsum[15];
}

__global__ __launch_bounds__(128) void scan_bsum(int* __restrict__ bsum) {
  __shared__ int ws0;
  const int t = threadIdx.x, lane = t & 63, wv = t >> 6;
  int v = (t < NB_SCAN) ? bsum[t] : 0;
  int sv = v;
  #pragma unroll
  for (int d = 1; d < 64; d <<= 1) {
    int u = __shfl_up(sv, d, 64);
    if (lane >= d) sv += u;
  }
  if (wv == 0 && lane == 63) ws0 = sv;
  __syncthreads();
  int excl = (wv ? ws0 : 0) + (sv - v);
  if (t < NB_SCAN) bsum[t] = excl;
}

__global__ __launch_bounds__(1024) void scan_add(int* __restrict__ off,
                                                 const int* __restrict__ bsum) {
  int i = blockIdx.x * 1024 + threadIdx.x;
  if (i < NN) off[i] += bsum[blockIdx.x];
  if (i == 0) off[NN] = NE;
}

// ---------------- counting-sort fill: CSR edge list with precomputed coef ----------------
__global__ void fill_kernel(const int* __restrict__ src, const int* __restrict__ dst,
                            const float* __restrict__ dinv, const int* __restrict__ off,
                            int* __restrict__ cursor, int2* __restrict__ einfo) {
  int i = blockIdx.x * blockDim.x + threadIdx.x;
  int n = gridDim.x * blockDim.x;
  for (; i < NE; i += n) {
    int s = src[i], d = dst[i];
    int pos = off[d] + atomicAdd(&cursor[d], 1);
    einfo[pos] = make_int2(s, __float_as_int(dinv[s] * dinv[d]));
  }
}

// ---------------- MFMA GEMM v3: B in LDS, grid-stride tiles, A-prefetch ----------------
// 512 blocks x 256 thr; wt staged to LDS once (padded 136 stride); each wave
// owns 16 rows/tile, loops tiles with next-tile A prefetched before MFMAs.
// Epilogue via PER-WAVE LDS slice (same-wave DS is in-order -> no barrier).
template<int NOUT, bool AF32>
__global__ __launch_bounds__(256) void mfma_gemm(
    const void* __restrict__ in_, const unsigned short* __restrict__ wt,
    unsigned short* __restrict__ h, int ntiles)
{
  constexpr int NCT = NOUT / 16;
  constexpr int LDW = 136;                 // 272B row stride: 16B-aligned, ~2-way banks
  __shared__ unsigned short wl[NOUT * LDW];
  __shared__ unsigned short es[4 * 16 * LDW];
  const int t = threadIdx.x;
  const int w = t >> 6, l = t & 63;
  const int r16 = l & 15, kbase = (l >> 4) * 8;

  // stage wt -> LDS (coalesced uint4)
  const uint4* wt4 = (const uint4*)wt;
  #pragma unroll
  for (int i = 0; i < NOUT * 16 / 256; ++i) {
    int idx = t + i * 256;
    int n = idx >> 4, g = idx & 15;
    *(uint4*)&wl[n * LDW + g * 8] = wt4[idx];
  }
  __syncthreads();

  unsigned short* esw = &es[w * 16 * LDW];
  const float* inf = (const float*)in_;
  const unsigned short* inb = (const unsigned short*)in_;

  int tile = blockIdx.x;
  if (tile >= ntiles) return;

  float4  nf[8];
  short8v nb[4];
  {
    int grow = tile * 64 + w * 16 + r16; if (grow > NN - 1) grow = NN - 1;
    if constexpr (AF32) {
      #pragma unroll
      for (int kt = 0; kt < 4; ++kt) {
        const float* p = inf + (size_t)grow * 128 + kt * 32 + kbase;
        nf[kt * 2] = *(const float4*)p; nf[kt * 2 + 1] = *(const float4*)(p + 4);
      }
    } else {
      #pragma unroll
      for (int kt = 0; kt < 4; ++kt)
        nb[kt] = *(const short8v*)(inb + (size_t)grow * 128 + kt * 32 + kbase);
    }
  }

  while (true) {
    // consume prefetched A (convert if f32)
    short8v a[4];
    if constexpr (AF32) {
      #pragma unroll
      for (int kt = 0; kt < 4; ++kt) {
        float4 u0 = nf[kt * 2], u1 = nf[kt * 2 + 1];
        short8v av;
        av[0] = (short)f2b(u0.x); av[1] = (short)f2b(u0.y);
        av[2] = (short)f2b(u0.z); av[3] = (short)f2b(u0.w);
        av[4] = (short)f2b(u1.x); av[5] = (short)f2b(u1.y);
        av[6] = (short)f2b(u1.z); av[7] = (short)f2b(u1.w);
        a[kt] = av;
      }
    } else {
      #pragma unroll
      for (int kt = 0; kt < 4; ++kt) a[kt] = nb[kt];
    }

    // issue next-tile A loads (latency hides under MFMAs+epilogue below)
    int next = tile + gridDim.x;
    if (next < ntiles) {
      int grow = next * 64 + w * 16 + r16; if (grow > NN - 1) grow = NN - 1;
      if constexpr (AF32) {
        #pragma unroll
        for (int kt = 0; kt < 4; ++kt) {
          const float* p = inf + (size_t)grow * 128 + kt * 32 + kbase;
          nf[kt * 2] = *(const float4*)p; nf[kt * 2 + 1] = *(const float4*)(p + 4);
        }
      } else {
        #pragma unroll
        for (int kt = 0; kt < 4; ++kt)
          nb[kt] = *(const short8v*)(inb + (size_t)grow * 128 + kt * 32 + kbase);
      }
    }

    float4v acc[NCT];
    #pragma unroll
    for (int c = 0; c < NCT; ++c) acc[c] = (float4v){0.f, 0.f, 0.f, 0.f};
    #pragma unroll
    for (int kt = 0; kt < 4; ++kt) {
      #pragma unroll
      for (int c = 0; c < NCT; ++c) {
        short8v b = *(const short8v*)&wl[(c * 16 + r16) * LDW + kt * 32 + kbase];
        acc[c] = __builtin_amdgcn_mfma_f32_16x16x32_bf16(a[kt], b, acc[c], 0, 0, 0);
      }
    }

    // per-wave epilogue: b16 scatter -> in-order DS -> uint4 coalesced stores
    const int q = l >> 4;
    #pragma unroll
    for (int c = 0; c < NCT; ++c) {
      #pragma unroll
      for (int r = 0; r < 4; ++r)
        esw[(q * 4 + r) * LDW + c * 16 + r16] = f2b(acc[c][r]);
    }
    constexpr int GPR2 = NOUT / 8;
    const int row0 = tile * 64 + w * 16;
    #pragma unroll
    for (int i = 0; i < 16 * GPR2 / 64; ++i) {
      int f = l + i * 64;
      int r = f / GPR2, g = f % GPR2;
      int row = row0 + r;
      if (row < NN)
        *(uint4*)(h + (size_t)row * NOUT + g * 8) = *(const uint4*)&esw[r * LDW + g * 8];
    }

    if (next >= ntiles) break;
    tile = next;
  }
}

// ---------------- aggregate (quad-edge): out[d] = b + dinv^2*h[d] + sum coef*h[src] ----------------
template<int NOUT, bool BF16RELU>
__global__ __launch_bounds__(256) void agg_kernel(
    const unsigned short* __restrict__ h, const int* __restrict__ off,
    const int2* __restrict__ einfo, const float* __restrict__ dinv,
    const float* __restrict__ bias, void* __restrict__ out_)
{
  constexpr int LPR = NOUT / 8;     // lanes per row (uint4): 16 or 8
  constexpr int GS  = 64 / LPR;     // edge slots per wave: 4 or 8
  const int w = (int)((blockIdx.x * 256 + threadIdx.x) >> 6);
  if (w >= NN) return;
  const int lane = threadIdx.x & 63;
  const int g = lane / LPR;
  const int c = lane % LPR;
  const int n0 = off[w], n1 = off[w + 1];
  const uint4* hu4 = (const uint4*)h;

  float acc[8];
  if (g == 0) {
    const float di = dinv[w];
    const float di2 = di * di;
    uint4 sv = hu4[(size_t)w * LPR + c];
    const float4* b4 = (const float4*)bias;
    float4 bl = b4[c * 2], bh = b4[c * 2 + 1];
    acc[0] = fmaf(bf_lo(sv.x), di2, bl.x);
    acc[1] = fmaf(bf_hi(sv.x), di2, bl.y);
    acc[2] = fmaf(bf_lo(sv.y), di2, bl.z);
    acc[3] = fmaf(bf_hi(sv.y), di2, bl.w);
    acc[4] = fmaf(bf_lo(sv.z), di2, bh.x);
    acc[5] = fmaf(bf_hi(sv.z), di2, bh.y);
    acc[6] = fmaf(bf_lo(sv.w), di2, bh.z);
    acc[7] = fmaf(bf_hi(sv.w), di2, bh.w);
  } else {
    #pragma unroll
    for (int j = 0; j < 8; ++j) acc[j] = 0.f;
  }

  for (int e = n0; e < n1; e += 2 * GS) {
    int e0 = e + g, e1 = e + GS + g;
    bool ok0 = e0 < n1, ok1 = e1 < n1;
    int2 s0 = einfo[ok0 ? e0 : n0];
    int2 s1 = einfo[ok1 ? e1 : n0];
    float c0 = ok0 ? __int_as_float(s0.y) : 0.f;
    float c1 = ok1 ? __int_as_float(s1.y) : 0.f;
    uint4 v0 = hu4[(size_t)s0.x * LPR + c];
    uint4 v1 = hu4[(size_t)s1.x * LPR + c];
    acc[0] = fmaf(bf_lo(v0.x), c0, acc[0]);
    acc[1] = fmaf(bf_hi(v0.x), c0, acc[1]);
    acc[2] = fmaf(bf_lo(v0.y), c0, acc[2]);
    acc[3] = fmaf(bf_hi(v0.y), c0, acc[3]);
    acc[4] = fmaf(bf_lo(v0.z), c0, acc[4]);
    acc[5] = fmaf(bf_hi(v0.z), c0, acc[5]);
    acc[6] = fmaf(bf_lo(v0.w), c0, acc[6]);
    acc[7] = fmaf(bf_hi(v0.w), c0, acc[7]);
    acc[0] = fmaf(bf_lo(v1.x), c1, acc[0]);
    acc[1] = fmaf(bf_hi(v1.x), c1, acc[1]);
    acc[2] = fmaf(bf_lo(v1.y), c1, acc[2]);
    acc[3] = fmaf(bf_hi(v1.y), c1, acc[3]);
    acc[4] = fmaf(bf_lo(v1.z), c1, acc[4]);
    acc[5] = fmaf(bf_hi(v1.z), c1, acc[5]);
    acc[6] = fmaf(bf_lo(v1.w), c1, acc[6]);
    acc[7] = fmaf(bf_hi(v1.w), c1, acc[7]);
  }

  #pragma unroll
  for (int j = 0; j < 8; ++j) {
    #pragma unroll
    for (int m = LPR; m < 64; m <<= 1)
      acc[j] += __shfl_xor(acc[j], m, 64);
  }

  if (g == 0) {
    if constexpr (BF16RELU) {
      uint4 o;
      o.x = (unsigned)f2b(fmaxf(acc[0], 0.f)) | ((unsigned)f2b(fmaxf(acc[1], 0.f)) << 16);
      o.y = (unsigned)f2b(fmaxf(acc[2], 0.f)) | ((unsigned)f2b(fmaxf(acc[3], 0.f)) << 16);
      o.z = (unsigned)f2b(fmaxf(acc[4], 0.f)) | ((unsigned)f2b(fmaxf(acc[5], 0.f)) << 16);
      o.w = (unsigned)f2b(fmaxf(acc[6], 0.f)) | ((unsigned)f2b(fmaxf(acc[7], 0.f)) << 16);
      ((uint4*)out_)[(size_t)w * LPR + c] = o;
    } else {
      float4 o0, o1;
      o0.x = acc[0]; o0.y = acc[1]; o0.z = acc[2]; o0.w = acc[3];
      o1.x = acc[4]; o1.y = acc[5]; o1.z = acc[6]; o1.w = acc[7];
      ((float4*)out_)[(size_t)w * LPR * 2 + c * 2]     = o0;
      ((float4*)out_)[(size_t)w * LPR * 2 + c * 2 + 1] = o1;
    }
  }
}

extern "C" void kernel_launch(void* const* d_in, const int* in_sizes, int n_in,
                              void* d_out, int out_size, void* d_ws, size_t ws_size,
                              hipStream_t stream) {
  const float* x  = (const float*)d_in[0];
  const int*   ei = (const int*)d_in[1];
  const float* W1 = (const float*)d_in[2];
  const float* b1 = (const float*)d_in[3];
  const float* W2 = (const float*)d_in[4];
  const float* b2 = (const float*)d_in[5];
  const float* W3 = (const float*)d_in[6];
  const float* b3 = (const float*)d_in[7];
  float* out = (float*)d_out;

  const int* src = ei;
  const int* dst = ei + NE;

  // workspace layout (float elements)
  float* ws = (float*)d_ws;
  int*   deg    = (int*)ws;                         // NN
  float* dinv   = ws + NN;                          // NN
  int*   off    = (int*)(ws + 2 * NN);              // NN+4
  int*   cursor = (int*)(ws + 3 * NN + 4);          // NN
  int*   bsum   = (int*)(ws + 4 * NN + 4);          // 128
  int2*  einfo  = (int2*)(ws + 4 * NN + 132);       // NE int2
  unsigned short* wt1 = (unsigned short*)(ws + 4 * NN + 132 + 2 * NE);  // 16384 bf16
  unsigned short* wt2 = wt1 + 16384;
  unsigned short* wt3 = wt2 + 16384;
  unsigned short* hA  = (unsigned short*)(ws + 4 * NN + 132 + 2 * NE + 20480); // NN*128 bf16
  unsigned short* hB  = hA + (size_t)NN * 128;                                 // NN*128 bf16

  hipMemsetAsync(deg, 0, NN * sizeof(int), stream);
  hipMemsetAsync(cursor, 0, NN * sizeof(int), stream);
  wprep_kernel<<<160, 256, 0, stream>>>(W1, W2, W3, wt1, wt2, wt3);
  deg_kernel<<<1024, 256, 0, stream>>>(dst, deg);
  scan_blocks<<<NB_SCAN, 1024, 0, stream>>>(deg, off, bsum, dinv);
  scan_bsum<<<1, 128, 0, stream>>>(bsum);
  scan_add<<<NB_SCAN, 1024, 0, stream>>>(off, bsum);
  fill_kernel<<<1024, 256, 0, stream>>>(src, dst, dinv, off, cursor, einfo);

  const int AGG_BLOCKS = (NN * 64 + 255) / 256;   // one wave per node
  const int NT = (NN + 63) / 64;                  // 1563 row tiles
  const int GEMM_GRID = 512;                      // 2 blocks/CU, ~3 tiles each

  // layer 1
  mfma_gemm<128, true><<<GEMM_GRID, 256, 0, stream>>>(x, wt1, hA, NT);
  agg_kernel<128, true><<<AGG_BLOCKS, 256, 0, stream>>>(hA, off, einfo, dinv, b1, hB);
  // layer 2
  mfma_gemm<128, false><<<GEMM_GRID, 256, 0, stream>>>(hB, wt2, hA, NT);
  agg_kernel<128, true><<<AGG_BLOCKS, 256, 0, stream>>>(hA, off, einfo, dinv, b2, hB);
  // layer 3 (64-wide, f32 final out)
  mfma_gemm<64, false><<<GEMM_GRID, 256, 0, stream>>>(hB, wt3, hA, NT);
  agg_kernel<64, false><<<AGG_BLOCKS, 256, 0, stream>>>(hA, off, einfo, dinv, b3, out);
}